// Round 1
// baseline (1190.553 us; speedup 1.0000x reference)
//
#include <hip/hip_runtime.h>

// GCN layer: out = relu( segment_sum(norm * (x @ W^T)[col] -> row) + b )
// norm = deg^-1/2[row] * deg^-1/2[col], deg = bincount(row)
//
// Pipeline:
//  1. memset deg=0 (ws), out=0
//  2. deg_kernel: atomic bincount of row
//  3. transform:  y = x @ W^T          (ws)
//  4. dis_kernel: dis = deg>0 ? rsqrt(deg) : 0   (ws)
//  5. scatter:    atomicAdd(out[row], dis[row]*dis[col] * y[col])
//  6. epilogue:   out = relu(out + b)  (in place)

#define NF 48

__global__ void deg_kernel(const int* __restrict__ row, int* __restrict__ deg, int E) {
    int e = blockIdx.x * blockDim.x + threadIdx.x;
    if (e < E) atomicAdd(&deg[row[e]], 1);
}

__global__ void dis_kernel(const int* __restrict__ deg, float* __restrict__ dis, int N) {
    int i = blockIdx.x * blockDim.x + threadIdx.x;
    if (i < N) {
        int d = deg[i];
        dis[i] = (d > 0) ? rsqrtf((float)d) : 0.0f;
    }
}

// y[n][f] = sum_k x[n][k] * W[f][k]   (W is [out=48, in=48])
__global__ void transform_kernel(const float* __restrict__ x, const float* __restrict__ W,
                                 float* __restrict__ y, int total) {
    __shared__ float Ws[NF * NF];
    for (int i = threadIdx.x; i < NF * NF; i += blockDim.x) Ws[i] = W[i];
    __syncthreads();
    int idx = blockIdx.x * blockDim.x + threadIdx.x;
    if (idx >= total) return;
    int node = idx / NF;
    int f    = idx % NF;
    const float* xr = x + (size_t)node * NF;
    const float* wr = Ws + f * NF;
    float s = 0.0f;
#pragma unroll
    for (int k = 0; k < NF; k++) s = fmaf(xr[k], wr[k], s);
    y[idx] = s;
}

// 12 threads per edge, each thread handles one float4 (4 feats). 16 edges/block.
__global__ void scatter_kernel(const int* __restrict__ row, const int* __restrict__ col,
                               const float* __restrict__ dis,
                               const float4* __restrict__ y4,
                               float* __restrict__ out, int E) {
    int tid = threadIdx.x;
    int e = blockIdx.x * 16 + (tid / 12);
    int j = tid % 12;
    if (e >= E) return;
    int r = row[e];
    int c = col[e];
    float norm = dis[r] * dis[c];
    float4 v = y4[(size_t)c * 12 + j];
    float* dst = out + (size_t)r * NF + j * 4;
    atomicAdd(dst + 0, norm * v.x);
    atomicAdd(dst + 1, norm * v.y);
    atomicAdd(dst + 2, norm * v.z);
    atomicAdd(dst + 3, norm * v.w);
}

__global__ void epilogue_kernel(float* __restrict__ out, const float* __restrict__ b, int total) {
    int idx = blockIdx.x * blockDim.x + threadIdx.x;
    if (idx < total) {
        float v = out[idx] + b[idx % NF];
        out[idx] = v > 0.0f ? v : 0.0f;
    }
}

extern "C" void kernel_launch(void* const* d_in, const int* in_sizes, int n_in,
                              void* d_out, int out_size, void* d_ws, size_t ws_size,
                              hipStream_t stream) {
    const float* x    = (const float*)d_in[0];
    const int*   ei   = (const int*)d_in[1];
    const float* W    = (const float*)d_in[2];
    const float* bias = (const float*)d_in[3];
    float* out = (float*)d_out;

    const int N = in_sizes[0] / NF;
    const int E = in_sizes[1] / 2;
    const int* row = ei;         // edge_index[0]
    const int* col = ei + E;     // edge_index[1]

    // workspace layout
    char* ws = (char*)d_ws;
    int*   deg = (int*)ws;                              // N ints
    float* dis = (float*)(ws + (size_t)N * 4);          // N floats
    float* y   = (float*)(ws + (size_t)N * 8);          // N*48 floats
    float4* y4 = (float4*)y;

    hipMemsetAsync(deg, 0, (size_t)N * 4, stream);
    hipMemsetAsync(out, 0, (size_t)N * NF * 4, stream);

    deg_kernel<<<(E + 255) / 256, 256, 0, stream>>>(row, deg, E);
    transform_kernel<<<(N * NF + 255) / 256, 256, 0, stream>>>(x, W, y, N * NF);
    dis_kernel<<<(N + 255) / 256, 256, 0, stream>>>(deg, dis, N);
    scatter_kernel<<<(E + 15) / 16, 192, 0, stream>>>(row, col, dis, y4, out, E);
    epilogue_kernel<<<(N * NF + 255) / 256, 256, 0, stream>>>(out, bias, N * NF);
}

// Round 2
// 494.577 us; speedup vs baseline: 2.4072x; 2.4072x over previous
//
#include <hip/hip_runtime.h>

// GCN layer, pull-based:
//   deg = bincount(row); dis = deg>0 ? rsqrt(deg) : 0
//   rowptr = exclusive_scan(deg); csr_col[rowptr[r] + k] = col  (counting sort)
//   z[n,f] = dis[n] * (x[n] @ W^T)[f]
//   out[n,f] = relu( dis[n] * sum_{c in adj(n)} z[c,f] + b[f] )
// No float atomics: each output element is owned by exactly one thread.

#define NF 48

__global__ void deg_kernel(const int* __restrict__ row, int* __restrict__ deg, int E) {
    int e = blockIdx.x * blockDim.x + threadIdx.x;
    if (e < E) atomicAdd(&deg[row[e]], 1);
}

__global__ void dis_kernel(const int* __restrict__ deg, float* __restrict__ dis, int N) {
    int i = blockIdx.x * blockDim.x + threadIdx.x;
    if (i < N) {
        int d = deg[i];
        dis[i] = (d > 0) ? rsqrtf((float)d) : 0.0f;
    }
}

// Single-block exclusive scan: deg[0..N) -> rowptr[0..N]
__global__ void scan_kernel(const int* __restrict__ deg, int* __restrict__ rowptr, int N) {
    __shared__ int wsum[16];
    __shared__ int carry_s;
    if (threadIdx.x == 0) carry_s = 0;
    __syncthreads();
    const int lane  = threadIdx.x & 63;
    const int wave  = threadIdx.x >> 6;
    const int nwaves = blockDim.x >> 6;
    for (int base = 0; base < N; base += blockDim.x) {
        int i = base + threadIdx.x;
        int v = (i < N) ? deg[i] : 0;
        // inclusive scan within wave
        int incl = v;
        #pragma unroll
        for (int off = 1; off < 64; off <<= 1) {
            int t = __shfl_up(incl, off, 64);
            if (lane >= off) incl += t;
        }
        if (lane == 63) wsum[wave] = incl;
        __syncthreads();
        // exclusive scan of wave sums (done by wave 0)
        if (wave == 0 && lane < nwaves) {
            int ws = wsum[lane];
            int wincl = ws;
            #pragma unroll
            for (int off = 1; off < 16; off <<= 1) {
                int t = __shfl_up(wincl, off, 16);
                if ((lane & 15) >= off) wincl += t;
            }
            wsum[lane] = wincl - ws;  // exclusive offset of this wave
        }
        __syncthreads();
        int excl = carry_s + wsum[wave] + (incl - v);
        if (i < N) rowptr[i] = excl;
        __syncthreads();  // everyone done reading carry_s/wsum
        if (threadIdx.x == blockDim.x - 1) carry_s += wsum[wave] + incl;  // chunk total
        __syncthreads();
    }
    if (threadIdx.x == 0) rowptr[N] = carry_s;
}

__global__ void fill_kernel(const int* __restrict__ row, const int* __restrict__ col,
                            const int* __restrict__ rowptr, int* __restrict__ cursor,
                            int* __restrict__ csr_col, int E) {
    int e = blockIdx.x * blockDim.x + threadIdx.x;
    if (e >= E) return;
    int r = row[e];
    int pos = rowptr[r] + atomicAdd(&cursor[r], 1);
    csr_col[pos] = col[e];
}

// z[n][f] = dis[n] * sum_k x[n][k] * W[f][k]
__global__ void transform_kernel(const float* __restrict__ x, const float* __restrict__ W,
                                 const float* __restrict__ dis, float* __restrict__ z, int total) {
    __shared__ float Ws[NF * NF];
    for (int i = threadIdx.x; i < NF * NF; i += blockDim.x) Ws[i] = W[i];
    __syncthreads();
    int idx = blockIdx.x * blockDim.x + threadIdx.x;
    if (idx >= total) return;
    int node = idx / NF;
    int f    = idx % NF;
    const float* xr = x + (size_t)node * NF;
    const float* wr = Ws + f * NF;
    float s = 0.0f;
#pragma unroll
    for (int k = 0; k < NF; k++) s = fmaf(xr[k], wr[k], s);
    z[idx] = dis[node] * s;
}

// 48 threads per node (4 nodes per 192-thread block); no atomics.
__global__ void gather_kernel(const int* __restrict__ rowptr, const int* __restrict__ csr_col,
                              const float* __restrict__ z, const float* __restrict__ dis,
                              const float* __restrict__ b, float* __restrict__ out, int N) {
    int n = blockIdx.x * 4 + threadIdx.x / NF;
    int f = threadIdx.x % NF;
    if (n >= N) return;
    int s = rowptr[n];
    int t = rowptr[n + 1];
    float acc = 0.0f;
    for (int k = s; k < t; k++) {
        int c = csr_col[k];                 // broadcast across the 48 threads
        acc += z[(size_t)c * NF + f];       // coalesced 192B row read
    }
    float v = dis[n] * acc + b[f];
    out[(size_t)n * NF + f] = v > 0.0f ? v : 0.0f;
}

extern "C" void kernel_launch(void* const* d_in, const int* in_sizes, int n_in,
                              void* d_out, int out_size, void* d_ws, size_t ws_size,
                              hipStream_t stream) {
    const float* x    = (const float*)d_in[0];
    const int*   ei   = (const int*)d_in[1];
    const float* W    = (const float*)d_in[2];
    const float* bias = (const float*)d_in[3];
    float* out = (float*)d_out;

    const int N = in_sizes[0] / NF;
    const int E = in_sizes[1] / 2;
    const int* row = ei;         // edge_index[0]
    const int* col = ei + E;     // edge_index[1]

    // workspace layout (bytes):
    //   z:       N*NF*4   (19.2 MB)  [16B aligned at base]
    //   csr_col: E*4      ( 6.4 MB)
    //   deg:     N*4
    //   cursor:  N*4
    //   dis:     N*4
    //   rowptr:  (N+1)*4
    char* ws = (char*)d_ws;
    float* z       = (float*)ws;                         ws += (size_t)N * NF * 4;
    int*   csr_col = (int*)ws;                           ws += (size_t)E * 4;
    int*   deg     = (int*)ws;                           ws += (size_t)N * 4;
    int*   cursor  = (int*)ws;                           ws += (size_t)N * 4;
    float* dis     = (float*)ws;                         ws += (size_t)N * 4;
    int*   rowptr  = (int*)ws;

    hipMemsetAsync(deg,    0, (size_t)N * 4, stream);
    hipMemsetAsync(cursor, 0, (size_t)N * 4, stream);

    deg_kernel<<<(E + 255) / 256, 256, 0, stream>>>(row, deg, E);
    dis_kernel<<<(N + 255) / 256, 256, 0, stream>>>(deg, dis, N);
    scan_kernel<<<1, 1024, 0, stream>>>(deg, rowptr, N);
    fill_kernel<<<(E + 255) / 256, 256, 0, stream>>>(row, col, rowptr, cursor, csr_col, E);
    transform_kernel<<<(N * NF + 255) / 256, 256, 0, stream>>>(x, W, dis, z, N * NF);
    gather_kernel<<<(N + 3) / 4, 192, 0, stream>>>(rowptr, csr_col, z, dis, bias, out, N);
}

// Round 3
// 374.722 us; speedup vs baseline: 3.1772x; 1.3198x over previous
//
#include <hip/hip_runtime.h>

// GCN layer, pull-based with multi-block CSR build:
//   deg = bincount(row); rowptr = exclusive_scan(deg)  [3-pass multi-block scan]
//   dis = deg>0 ? rsqrt(deg) : 0                        [fused into scan apply]
//   cursor = copy(rowptr); csr_col[atomicAdd(cursor[r])] = col
//   z[n,f] = dis[n] * (x[n] @ W^T)[f]
//   out[n,f] = relu( dis[n] * sum_{c in adj(n)} z[c,f] + b[f] )
// Gather: one wave per node, lanes 0..47 = features, edge ids broadcast via shfl.

#define NF 48
#define SCAN_B 256

__global__ void deg_kernel(const int* __restrict__ row, int* __restrict__ deg, int E) {
    int e = blockIdx.x * blockDim.x + threadIdx.x;
    if (e < E) atomicAdd(&deg[row[e]], 1);
}

// Pass A: per-block reduction of deg -> bsum[block]
__global__ void reduce_kernel(const int* __restrict__ deg, int* __restrict__ bsum, int N) {
    int i = blockIdx.x * SCAN_B + threadIdx.x;
    int v = (i < N) ? deg[i] : 0;
    #pragma unroll
    for (int off = 32; off >= 1; off >>= 1) v += __shfl_xor(v, off, 64);
    __shared__ int ws[SCAN_B / 64];
    int wave = threadIdx.x >> 6, lane = threadIdx.x & 63;
    if (lane == 0) ws[wave] = v;
    __syncthreads();
    if (threadIdx.x == 0) {
        int s = 0;
        #pragma unroll
        for (int w = 0; w < SCAN_B / 64; w++) s += ws[w];
        bsum[blockIdx.x] = s;
    }
}

// Pass B: single-block exclusive scan of bsum[0..B) in place (B ~ 391)
__global__ void scan_bsum_kernel(int* __restrict__ bsum, int B) {
    __shared__ int wsum[16];
    __shared__ int carry_s;
    if (threadIdx.x == 0) carry_s = 0;
    __syncthreads();
    const int lane = threadIdx.x & 63;
    const int wave = threadIdx.x >> 6;
    const int nw = blockDim.x >> 6;
    for (int base = 0; base < B; base += blockDim.x) {
        int i = base + threadIdx.x;
        int v = (i < B) ? bsum[i] : 0;
        int incl = v;
        #pragma unroll
        for (int off = 1; off < 64; off <<= 1) {
            int t = __shfl_up(incl, off, 64);
            if (lane >= off) incl += t;
        }
        if (lane == 63) wsum[wave] = incl;
        __syncthreads();
        if (wave == 0 && lane < nw) {
            int wsv = wsum[lane];
            int wincl = wsv;
            #pragma unroll
            for (int off = 1; off < 16; off <<= 1) {
                int t = __shfl_up(wincl, off, 16);
                if ((lane & 15) >= off) wincl += t;
            }
            wsum[lane] = wincl - wsv;
        }
        __syncthreads();
        if (i < B) bsum[i] = carry_s + wsum[wave] + (incl - v);
        __syncthreads();
        if (threadIdx.x == blockDim.x - 1) carry_s += wsum[wave] + incl;
        __syncthreads();
    }
}

// Pass C: per-block scan of deg + block offset -> rowptr; also dis = rsqrt(deg)
__global__ void apply_kernel(const int* __restrict__ deg, const int* __restrict__ bsum,
                             int* __restrict__ rowptr, float* __restrict__ dis,
                             int N, int E) {
    int i = blockIdx.x * SCAN_B + threadIdx.x;
    int v = (i < N) ? deg[i] : 0;
    const int lane = threadIdx.x & 63;
    const int wave = threadIdx.x >> 6;
    int incl = v;
    #pragma unroll
    for (int off = 1; off < 64; off <<= 1) {
        int t = __shfl_up(incl, off, 64);
        if (lane >= off) incl += t;
    }
    __shared__ int ws[SCAN_B / 64];
    if (lane == 63) ws[wave] = incl;
    __syncthreads();
    int woff = 0;
    #pragma unroll
    for (int w = 0; w < SCAN_B / 64; w++) if (w < wave) woff += ws[w];
    if (i < N) {
        rowptr[i] = bsum[blockIdx.x] + woff + (incl - v);
        dis[i] = (v > 0) ? rsqrtf((float)v) : 0.0f;
    }
    if (i == 0) rowptr[N] = E;   // sum of deg == E
}

__global__ void fill_kernel(const int* __restrict__ row, const int* __restrict__ col,
                            int* __restrict__ cursor, int* __restrict__ csr_col, int E) {
    int e = blockIdx.x * blockDim.x + threadIdx.x;
    if (e >= E) return;
    int pos = atomicAdd(&cursor[row[e]], 1);
    csr_col[pos] = col[e];
}

// z[n][f] = dis[n] * sum_k x[n][k] * W[f][k]
__global__ void transform_kernel(const float* __restrict__ x, const float* __restrict__ W,
                                 const float* __restrict__ dis, float* __restrict__ z, int total) {
    __shared__ float Ws[NF * NF];
    for (int i = threadIdx.x; i < NF * NF; i += blockDim.x) Ws[i] = W[i];
    __syncthreads();
    int idx = blockIdx.x * blockDim.x + threadIdx.x;
    if (idx >= total) return;
    int node = idx / NF;
    int f    = idx % NF;
    const float* xr = x + (size_t)node * NF;
    const float* wr = Ws + f * NF;
    float s = 0.0f;
#pragma unroll
    for (int k = 0; k < NF; k++) s = fmaf(xr[k], wr[k], s);
    z[idx] = dis[node] * s;
}

// One wave per node. Lanes 0..47 accumulate features; all 64 lanes stage edge ids.
__global__ void gather_kernel(const int* __restrict__ rowptr, const int* __restrict__ csr_col,
                              const float* __restrict__ z, const float* __restrict__ dis,
                              const float* __restrict__ b, float* __restrict__ out, int N) {
    const int lane = threadIdx.x & 63;
    const int wave = threadIdx.x >> 6;
    int n = blockIdx.x * 4 + wave;
    if (n >= N) return;
    int s = rowptr[n];
    int t = rowptr[n + 1];
    float acc = 0.0f;
    for (int base = s; base < t; base += 64) {
        int cnt = min(64, t - base);
        int cv = (lane < cnt) ? csr_col[base + lane] : 0;
        int k = 0;
        for (; k + 4 <= cnt; k += 4) {
            int c0 = __shfl(cv, k,     64);
            int c1 = __shfl(cv, k + 1, 64);
            int c2 = __shfl(cv, k + 2, 64);
            int c3 = __shfl(cv, k + 3, 64);
            if (lane < NF) {
                float v0 = z[(size_t)c0 * NF + lane];
                float v1 = z[(size_t)c1 * NF + lane];
                float v2 = z[(size_t)c2 * NF + lane];
                float v3 = z[(size_t)c3 * NF + lane];
                acc += (v0 + v1) + (v2 + v3);
            }
        }
        for (; k < cnt; k++) {
            int c = __shfl(cv, k, 64);
            if (lane < NF) acc += z[(size_t)c * NF + lane];
        }
    }
    if (lane < NF) {
        float v = dis[n] * acc + b[lane];
        out[(size_t)n * NF + lane] = v > 0.0f ? v : 0.0f;
    }
}

extern "C" void kernel_launch(void* const* d_in, const int* in_sizes, int n_in,
                              void* d_out, int out_size, void* d_ws, size_t ws_size,
                              hipStream_t stream) {
    const float* x    = (const float*)d_in[0];
    const int*   ei   = (const int*)d_in[1];
    const float* W    = (const float*)d_in[2];
    const float* bias = (const float*)d_in[3];
    float* out = (float*)d_out;

    const int N = in_sizes[0] / NF;
    const int E = in_sizes[1] / 2;
    const int* row = ei;         // edge_index[0]
    const int* col = ei + E;     // edge_index[1]
    const int NB = (N + SCAN_B - 1) / SCAN_B;   // scan blocks (~391)

    // workspace layout
    char* ws = (char*)d_ws;
    float* z       = (float*)ws;                 ws += (size_t)N * NF * 4;
    int*   csr_col = (int*)ws;                   ws += (size_t)E * 4;
    int*   deg     = (int*)ws;                   ws += (size_t)N * 4;
    int*   cursor  = (int*)ws;                   ws += (size_t)N * 4;
    float* dis     = (float*)ws;                 ws += (size_t)N * 4;
    int*   rowptr  = (int*)ws;                   ws += (size_t)(N + 1) * 4;
    int*   bsum    = (int*)ws;                   ws += (size_t)NB * 4;

    hipMemsetAsync(deg, 0, (size_t)N * 4, stream);

    deg_kernel<<<(E + 255) / 256, 256, 0, stream>>>(row, deg, E);
    reduce_kernel<<<NB, SCAN_B, 0, stream>>>(deg, bsum, N);
    scan_bsum_kernel<<<1, 512, 0, stream>>>(bsum, NB);
    apply_kernel<<<NB, SCAN_B, 0, stream>>>(deg, bsum, rowptr, dis, N, E);
    hipMemcpyAsync(cursor, rowptr, (size_t)N * 4, hipMemcpyDeviceToDevice, stream);
    fill_kernel<<<(E + 255) / 256, 256, 0, stream>>>(row, col, cursor, csr_col, E);
    transform_kernel<<<(N * NF + 255) / 256, 256, 0, stream>>>(x, W, dis, z, N * NF);
    gather_kernel<<<(N + 3) / 4, 256, 0, stream>>>(rowptr, csr_col, z, dis, bias, out, N);
}